// Round 8
// baseline (2310.043 us; speedup 1.0000x reference)
//
#include <hip/hip_runtime.h>
#include <cstdint>
#include <cstddef>

// Problem constants
#define BB   64     // batch
#define TT   512    // time steps
#define HH   256    // hidden
#define G4   1024   // 4*H
#define NL   8      // layers
#define NW   32     // workgroups per layer (hidden-unit slices)
#define HPW  8      // hidden units per WG
#define NR   32     // gate rows per WG (4 gates * HPW)

#define POISON ((int)0xAAAAAAAA)

typedef _Float16 half8 __attribute__((ext_vector_type(8)));
typedef float   floatx4 __attribute__((ext_vector_type(4)));
typedef int     intx4  __attribute__((ext_vector_type(4)));

__device__ __forceinline__ float sigm(float v)   { return 1.0f / (1.0f + __expf(-v)); }
__device__ __forceinline__ float tanh_f(float v) { return 1.0f - 2.0f / (__expf(2.0f * v) + 1.0f); }

// ---- coherent access (sc0 sc1: bypass L1+L2, served at the IF$ coherence point).
// Polls MUST be uncached so retries observe fresh data.
__device__ __forceinline__ void gload4i_x(intx4& d, const _Float16* p) {
  asm volatile("global_load_dwordx4 %0, %1, off sc0 sc1" : "=v"(d) : "v"(p) : "memory");
}
__device__ __forceinline__ void gstore4i_x(_Float16* p, intx4 d) {
  asm volatile("global_store_dwordx4 %0, %1, off sc0 sc1" :: "v"(p), "v"(d) : "memory");
}
__device__ __forceinline__ void wait_vm0() {
  asm volatile("s_waitcnt vmcnt(0)" ::: "memory");
}
__device__ __forceinline__ half8 as_h8(intx4 v) {
  union { intx4 i; half8 h; } u; u.i = v; return u.h;
}

// hseq layout per layer: [t][kblk=H/8=32][b=64][8] fp16 (MFMA A-fragment friendly)
// Every 16B fragment (kblk,b) is written by exactly ONE producer store -> the
// fragment doubles as its own ready-flag (sentinel-validated, write-once slots).
#define TSTRIDE ((size_t)32 * BB * 8)         // 16384 elems per t
#define LSTRIDE ((size_t)TT * TSTRIDE)        // 8,388,608 elems per layer (16 MB)

// ---------------------------------------------------------------------------
// xg0 table: table[v][n] = sum_e emb[v][e] * Wih0[n][e]   (biases NOT included)
__global__ void build_xg0(const float* __restrict__ emb, const float* __restrict__ Wih0,
                          float* __restrict__ table) {
  int i = blockIdx.x * 256 + threadIdx.x;
  if (i >= 23 * G4) return;
  int v = i >> 10, n = i & (G4 - 1);
  float a = 0.f;
#pragma unroll
  for (int e = 0; e < 16; ++e) a += emb[v * 16 + e] * Wih0[n * 16 + e];
  table[i] = a;
}

// ---------------------------------------------------------------------------
// Persistent pipelined LSTM. grid = 256 blocks (NL layers x NW slices), 256 thr.
// DATA-AS-FLAG sync: hseq is pre-poisoned to 0xAA; producers store h fragments
// (nudging any dword that equals the sentinel by ^1); consumers poll-load the
// exact fragments they need until every dword != sentinel. This removes the
// flag indirection: no publish-ack, no flag travel, no separate poll RT --
// the R2-R7 chain of ~4 coherence round trips per step becomes ~1.5.
__global__ __launch_bounds__(256, 1) void lstm_pipeline(
    const int*   __restrict__ x,         // [B][T]
    const float* __restrict__ Wih_rest,  // [7][1024][256]
    const float* __restrict__ Whh,       // [8][1024][256]
    const float* __restrict__ bih,       // [8][1024]
    const float* __restrict__ bhh,       // [8][1024]
    const float* __restrict__ xg0t,      // [23][1024]
    _Float16* __restrict__ hseq)         // NL * LSTRIDE fp16 (pre-poisoned 0xAA)
{
  const int l   = blockIdx.x & 7;
  const int w   = blockIdx.x >> 3;
  const int tid = threadIdx.x;
  const int lane = tid & 63;
  const int p    = tid >> 6;        // wave index = M-tile index (batch/16)
  const int bb   = tid & 63;

  __shared__ __align__(16) _Float16 wlds[64 * NR * 8]; // [kc 0..63][n 0..31][8]
  __shared__ float  glds[BB * 33];                     // padded
  __shared__ __align__(16) _Float16 hl[2][BB * 8];     // double-buffered h stage
  __shared__ float  blds[NR];
  __shared__ float  tlds[23 * NR];

  // ---- one-time init: gather this WG's 32 gate rows into LDS as fp16 ----
  for (int idx = tid; idx < 64 * NR; idx += 256) {
    int kc = idx >> 5;          // 0..31 input half, 32..63 recurrent half
    int n  = idx & 31;
    int g = n >> 3, jl = n & 7;
    int gr = g * 256 + w * HPW + jl;
    float v[8];
    if (kc < 32) {
      if (l == 0) { for (int j = 0; j < 8; ++j) v[j] = 0.f; }
      else {
        const float* src = Wih_rest + ((size_t)(l - 1) * G4 + gr) * HH + kc * 8;
        for (int j = 0; j < 8; ++j) v[j] = src[j];
      }
    } else {
      const float* src = Whh + ((size_t)l * G4 + gr) * HH + (kc - 32) * 8;
      for (int j = 0; j < 8; ++j) v[j] = src[j];
    }
    _Float16* dst = wlds + (size_t)idx * 8;
    for (int j = 0; j < 8; ++j) dst[j] = (_Float16)v[j];
  }
  if (tid < NR) {
    int g = tid >> 3, jl = tid & 7;
    int gr = g * 256 + w * HPW + jl;
    blds[tid] = bih[l * G4 + gr] + bhh[l * G4 + gr];
  }
  if (l == 0) {
    for (int idx = tid; idx < 23 * NR; idx += 256) {
      int v = idx >> 5, n = idx & 31;
      int g = n >> 3, jl = n & 7;
      tlds[idx] = xg0t[v * G4 + g * 256 + w * HPW + jl];
    }
  }
  __syncthreads();

  float c0 = 0.f, c1 = 0.f;

  const int arow = p * 16 + (lane & 15);  // A-fragment batch row
  const int kq   = lane >> 4;             // quarter-wave -> k chunk within tile
  const int n0   = lane & 15;             // B-fragment col (tile 0)
  const int n1   = 16 + n0;               // B-fragment col (tile 1)

  const _Float16* hin  = hseq + (size_t)(l > 0 ? l - 1 : 0) * LSTRIDE;
  _Float16*       hrec = hseq + (size_t)l * LSTRIDE;

  for (int t = 0; t < TT; ++t) {
    // ---- self-synchronizing poll-loads: each wave loads exactly its own
    //      MFMA fragments and retries until all dwords are non-sentinel ----
    intx4 fa[8], fb[8];
    {
      const _Float16* ainA = hin + (size_t)t * TSTRIDE;
      const _Float16* ainB = hrec + (size_t)(t > 0 ? t - 1 : 0) * TSTRIDE;
      for (;;) {
        if (l > 0) {
#pragma unroll
          for (int kt = 0; kt < 8; ++kt) {
            int kc = kt * 4 + kq;
            gload4i_x(fa[kt], ainA + ((size_t)(kc * 64 + arow) << 3));
          }
        }
        if (t > 0) {
#pragma unroll
          for (int kt = 0; kt < 8; ++kt) {
            int kc = kt * 4 + kq;
            gload4i_x(fb[kt], ainB + ((size_t)(kc * 64 + arow) << 3));
          }
        }
        wait_vm0();
        int ok = 1;
        if (l > 0) {
#pragma unroll
          for (int kt = 0; kt < 8; ++kt) {
#pragma unroll
            for (int j = 0; j < 4; ++j) ok &= (fa[kt][j] != POISON);
          }
        }
        if (t > 0) {
#pragma unroll
          for (int kt = 0; kt < 8; ++kt) {
#pragma unroll
            for (int j = 0; j < 4; ++j) ok &= (fb[kt][j] != POISON);
          }
        }
        if (__all(ok)) break;
        __builtin_amdgcn_s_sleep(1);
      }
    }

    floatx4 acc0 = {0.f, 0.f, 0.f, 0.f};
    floatx4 acc1 = {0.f, 0.f, 0.f, 0.f};
    if (l > 0) {
#pragma unroll
      for (int kt = 0; kt < 8; ++kt) {
        int kc = kt * 4 + kq;
        half8 w0 = *(const half8*)(wlds + ((kc * 32 + n0) << 3));
        half8 w1 = *(const half8*)(wlds + ((kc * 32 + n1) << 3));
        acc0 = __builtin_amdgcn_mfma_f32_16x16x32_f16(as_h8(fa[kt]), w0, acc0, 0, 0, 0);
        acc1 = __builtin_amdgcn_mfma_f32_16x16x32_f16(as_h8(fa[kt]), w1, acc1, 0, 0, 0);
      }
    }
    if (t > 0) {
#pragma unroll
      for (int kt = 0; kt < 8; ++kt) {
        int kc = kt * 4 + kq;
        half8 w0 = *(const half8*)(wlds + (((32 + kc) * 32 + n0) << 3));
        half8 w1 = *(const half8*)(wlds + (((32 + kc) * 32 + n1) << 3));
        acc0 = __builtin_amdgcn_mfma_f32_16x16x32_f16(as_h8(fb[kt]), w0, acc0, 0, 0, 0);
        acc1 = __builtin_amdgcn_mfma_f32_16x16x32_f16(as_h8(fb[kt]), w1, acc1, 0, 0, 0);
      }
    }

    // ---- gates to LDS (C layout: col=lane&15, row=quad*4+reg) ----
    {
      int rbase = p * 16 + kq * 4;
#pragma unroll
      for (int r = 0; r < 4; ++r) {
        glds[(rbase + r) * 33 + n0]      = acc0[r];
        glds[(rbase + r) * 33 + 16 + n0] = acc1[r];
      }
    }
    __syncthreads();   // barrier B

    // ---- cell update: thread handles (bb, 2p) and (bb, 2p+1) ----
    {
      int xv = 0;
      if (l == 0) xv = x[bb * TT + t];
      float h0, h1;
#pragma unroll
      for (int q = 0; q < 2; ++q) {
        int j = 2 * p + q;
        float gi = glds[bb * 33 + j]      + blds[j];
        float gf = glds[bb * 33 + 8 + j]  + blds[8 + j];
        float gg = glds[bb * 33 + 16 + j] + blds[16 + j];
        float go = glds[bb * 33 + 24 + j] + blds[24 + j];
        if (l == 0) {
          const float* tb = tlds + xv * NR;
          gi += tb[j]; gf += tb[8 + j]; gg += tb[16 + j]; go += tb[24 + j];
        }
        float iv = sigm(gi), fv = sigm(gf), gv = tanh_f(gg), ov = sigm(go);
        float cv = (q == 0) ? c0 : c1;
        cv = fv * cv + iv * gv;
        float hv = ov * tanh_f(cv);
        if (q == 0) { c0 = cv; h0 = hv; } else { c1 = cv; h1 = hv; }
      }
      hl[t & 1][bb * 8 + 2 * p]     = (_Float16)h0;
      hl[t & 1][bb * 8 + 2 * p + 1] = (_Float16)h1;
    }
    __syncthreads();   // barrier C: hl[t&1] complete

    // ---- publish: wave0 stores the 1KB slice contiguously (16B/lane),
    //      sentinel-nudged, NO waitcnt, NO flag. Fire and forget. ----
    if (tid < 64) {
      intx4 hv = *(const intx4*)(hl[t & 1] + tid * 8);
#pragma unroll
      for (int j = 0; j < 4; ++j)
        if (hv[j] == POISON) hv[j] ^= 1;   // keep sentinel unambiguous (1-ulp nudge)
      gstore4i_x(hrec + (size_t)t * TSTRIDE + ((size_t)w * 64 + tid) * 8, hv);
    }
    // no barrier: consumers self-sync on the data; hl double-buffer protects reuse
  }
}

// ---------------------------------------------------------------------------
// Final projection: out[b][t][v] = h7[b][t][:] . fc_w[v][:] + fc_b[v]
__global__ __launch_bounds__(256) void fc_kernel(
    const _Float16* __restrict__ hseq7,  // [T][32][64][8] fp16
    const float* __restrict__ fcw,       // [23][256]
    const float* __restrict__ fcb,       // [23]
    float* __restrict__ out)             // [64][512][23]
{
  const int t = blockIdx.x;
  const int tid = threadIdx.x;
  __shared__ __align__(16) _Float16 hbuf[32 * 64 * 8];
  __shared__ float wbuf[23 * 256];
  __shared__ float bbuf[24];

  const _Float16* src = hseq7 + (size_t)t * TSTRIDE;
  for (int i = tid; i < 32 * 64; i += 256)
    ((half8*)hbuf)[i] = ((const half8*)src)[i];
  for (int i = tid; i < 23 * 256; i += 256) wbuf[i] = fcw[i];
  if (tid < 23) bbuf[tid] = fcb[tid];
  __syncthreads();

  for (int o = tid; o < 64 * 23; o += 256) {
    int b = o / 23, v = o - b * 23;
    float acc = bbuf[v];
#pragma unroll 4
    for (int kc = 0; kc < 32; ++kc) {
      half8 hv = *(const half8*)(hbuf + ((kc * 64 + b) << 3));
      const float* wr = wbuf + v * 256 + kc * 8;
#pragma unroll
      for (int j = 0; j < 8; ++j) acc += (float)hv[j] * wr[j];
    }
    out[((size_t)b * TT + t) * 23 + v] = acc;
  }
}

// ---------------------------------------------------------------------------
extern "C" void kernel_launch(void* const* d_in, const int* in_sizes, int n_in,
                              void* d_out, int out_size, void* d_ws, size_t ws_size,
                              hipStream_t stream) {
  const int*   x        = (const int*)d_in[0];
  const float* emb      = (const float*)d_in[1];
  const float* Wih0     = (const float*)d_in[2];
  const float* Wih_rest = (const float*)d_in[3];
  const float* Whh      = (const float*)d_in[4];
  const float* bihp     = (const float*)d_in[5];
  const float* bhhp     = (const float*)d_in[6];
  const float* fcw      = (const float*)d_in[7];
  const float* fcb      = (const float*)d_in[8];
  float* out = (float*)d_out;

  char* ws = (char*)d_ws;
  // ws layout (proven footprint): table @16384 | hseq @131072 (128MB)
  float*    table = (float*)(ws + 16384);              // 23*1024*4 = 94208 B
  _Float16* hseq  = (_Float16*)(ws + 131072);          // 8 * 16 MB

  // Pre-poison hseq ourselves (~20us at HBM BW): the data-as-flag protocol's
  // ONLY precondition, guaranteed independent of harness poisoning semantics.
  hipMemsetAsync(hseq, 0xAA, NL * LSTRIDE * sizeof(_Float16), stream);
  build_xg0<<<(23 * G4 + 255) / 256, 256, 0, stream>>>(emb, Wih0, table);
  lstm_pipeline<<<NL * NW, 256, 0, stream>>>(x, Wih_rest, Whh, bihp, bhhp, table, hseq);
  fc_kernel<<<TT, 256, 0, stream>>>(hseq + (size_t)7 * LSTRIDE, fcw, fcb, out);
}

// Round 9
// 2099.487 us; speedup vs baseline: 1.1003x; 1.1003x over previous
//
#include <hip/hip_runtime.h>
#include <cstdint>
#include <cstddef>

// Problem constants
#define BB   64     // batch
#define TT   512    // time steps
#define HH   256    // hidden
#define G4   1024   // 4*H
#define NL   8      // layers
#define NW   32     // workgroups per layer (hidden-unit slices)
#define HPW  8      // hidden units per WG
#define NR   32     // gate rows per WG (4 gates * HPW)

#define POISON ((int)0xAAAAAAAA)

typedef _Float16 half8 __attribute__((ext_vector_type(8)));
typedef float   floatx4 __attribute__((ext_vector_type(4)));
typedef int     intx4  __attribute__((ext_vector_type(4)));

__device__ __forceinline__ float sigm(float v)   { return 1.0f / (1.0f + __expf(-v)); }
__device__ __forceinline__ float tanh_f(float v) { return 1.0f - 2.0f / (__expf(2.0f * v) + 1.0f); }

// ---- coherent access (sc0 sc1: bypass L1+L2, served at the IF$ coherence point) ----
__device__ __forceinline__ void gload4i_x(intx4& d, const _Float16* p) {
  asm volatile("global_load_dwordx4 %0, %1, off sc0 sc1" : "=v"(d) : "v"(p) : "memory");
}
__device__ __forceinline__ void gstore4i_x(_Float16* p, intx4 d) {
  asm volatile("global_store_dwordx4 %0, %1, off sc0 sc1" :: "v"(p), "v"(d) : "memory");
}
__device__ __forceinline__ void wait_vm0() {
  asm volatile("s_waitcnt vmcnt(0)" ::: "memory");
}
__device__ __forceinline__ half8 as_h8(intx4 v) {
  union { intx4 i; half8 h; } u; u.i = v; return u.h;
}
__device__ __forceinline__ int vld4(intx4 v) {
  return (v[0] != POISON) & (v[1] != POISON) & (v[2] != POISON) & (v[3] != POISON);
}

// hseq layout per layer: [t][kblk=H/8=32][b=64][8] fp16 (MFMA A-fragment friendly)
// Write-once slots; fragments are self-validating via the 0xAA sentinel.
#define TSTRIDE ((size_t)32 * BB * 8)         // 16384 elems per t
#define LSTRIDE ((size_t)TT * TSTRIDE)        // 8,388,608 elems per layer (16 MB)

// ---------------------------------------------------------------------------
// xg0 table: table[v][n] = sum_e emb[v][e] * Wih0[n][e]   (biases NOT included)
__global__ void build_xg0(const float* __restrict__ emb, const float* __restrict__ Wih0,
                          float* __restrict__ table) {
  int i = blockIdx.x * 256 + threadIdx.x;
  if (i >= 23 * G4) return;
  int v = i >> 10, n = i & (G4 - 1);
  float a = 0.f;
#pragma unroll
  for (int e = 0; e < 16; ++e) a += emb[v * 16 + e] * Wih0[n * 16 + e];
  table[i] = a;
}

// ---------------------------------------------------------------------------
// Persistent pipelined LSTM. grid = 256 blocks (NL layers x NW slices), 256 thr.
// R9 sync = R8's proven sentinel protocol with R7's traffic profile:
//  - RELEASE (1 coherence trip, was 2): wave0 stores the whole 1KB slice with
//    ONE sentinel-nudged instruction; NO vmcnt ack, NO flag. Fire-and-forget.
//  - DETECT (narrow): each wave spins on a single 16B fragment of the gating
//    half (recurrent B if t>0, else input A) -- flag-sized poll traffic.
//  - BULK: remaining fragments loaded uncached, every dword validated against
//    the sentinel; retry on rare stragglers. No ordering assumptions.
//  - No barrier A: waves acquire independently; barriers B/C resync the WG.
__global__ __launch_bounds__(256, 1) void lstm_pipeline(
    const int*   __restrict__ x,         // [B][T]
    const float* __restrict__ Wih_rest,  // [7][1024][256]
    const float* __restrict__ Whh,       // [8][1024][256]
    const float* __restrict__ bih,       // [8][1024]
    const float* __restrict__ bhh,       // [8][1024]
    const float* __restrict__ xg0t,      // [23][1024]
    _Float16* __restrict__ hseq)         // NL * LSTRIDE fp16 (pre-poisoned 0xAA)
{
  const int l   = blockIdx.x & 7;
  const int w   = blockIdx.x >> 3;
  const int tid = threadIdx.x;
  const int lane = tid & 63;
  const int p    = tid >> 6;        // wave index = M-tile index (batch/16)
  const int bb   = tid & 63;

  __shared__ __align__(16) _Float16 wlds[64 * NR * 8]; // [kc 0..63][n 0..31][8]
  __shared__ float  glds[BB * 33];                     // padded
  __shared__ __align__(16) _Float16 hl[2][BB * 8];     // double-buffered h stage
  __shared__ float  blds[NR];
  __shared__ float  tlds[23 * NR];

  // ---- one-time init: gather this WG's 32 gate rows into LDS as fp16 ----
  for (int idx = tid; idx < 64 * NR; idx += 256) {
    int kc = idx >> 5;          // 0..31 input half, 32..63 recurrent half
    int n  = idx & 31;
    int g = n >> 3, jl = n & 7;
    int gr = g * 256 + w * HPW + jl;
    float v[8];
    if (kc < 32) {
      if (l == 0) { for (int j = 0; j < 8; ++j) v[j] = 0.f; }
      else {
        const float* src = Wih_rest + ((size_t)(l - 1) * G4 + gr) * HH + kc * 8;
        for (int j = 0; j < 8; ++j) v[j] = src[j];
      }
    } else {
      const float* src = Whh + ((size_t)l * G4 + gr) * HH + (kc - 32) * 8;
      for (int j = 0; j < 8; ++j) v[j] = src[j];
    }
    _Float16* dst = wlds + (size_t)idx * 8;
    for (int j = 0; j < 8; ++j) dst[j] = (_Float16)v[j];
  }
  if (tid < NR) {
    int g = tid >> 3, jl = tid & 7;
    int gr = g * 256 + w * HPW + jl;
    blds[tid] = bih[l * G4 + gr] + bhh[l * G4 + gr];
  }
  if (l == 0) {
    for (int idx = tid; idx < 23 * NR; idx += 256) {
      int v = idx >> 5, n = idx & 31;
      int g = n >> 3, jl = n & 7;
      tlds[idx] = xg0t[v * G4 + g * 256 + w * HPW + jl];
    }
  }
  __syncthreads();

  float c0 = 0.f, c1 = 0.f;

  const int arow = p * 16 + (lane & 15);  // A-fragment batch row
  const int kq   = lane >> 4;             // quarter-wave -> k chunk within tile
  const int n0   = lane & 15;             // B-fragment col (tile 0)
  const int n1   = 16 + n0;               // B-fragment col (tile 1)

  const _Float16* hin  = hseq + (size_t)(l > 0 ? l - 1 : 0) * LSTRIDE;
  _Float16*       hrec = hseq + (size_t)l * LSTRIDE;

  for (int t = 0; t < TT; ++t) {
    const bool haveA = (l > 0);
    const bool haveB = (t > 0);
    intx4 fa[8], fb[8];
    const _Float16* pA = hin  + (size_t)t * TSTRIDE;
    const _Float16* pB = hrec + (size_t)(haveB ? t - 1 : 0) * TSTRIDE;
    const size_t f0 = ((size_t)(kq * 64 + arow)) << 3;   // kt=0 fragment offset

    // ---- narrow spin: one 16B fragment of the gating half ----
    if (haveB) {
      gload4i_x(fb[0], pB + f0); wait_vm0();
      while (!__all(vld4(fb[0]))) {
        __builtin_amdgcn_s_sleep(1);
        gload4i_x(fb[0], pB + f0); wait_vm0();
      }
    } else if (haveA) {
      gload4i_x(fa[0], pA + f0); wait_vm0();
      while (!__all(vld4(fa[0]))) {
        __builtin_amdgcn_s_sleep(1);
        gload4i_x(fa[0], pA + f0); wait_vm0();
      }
    }

    // ---- bulk: remaining fragments, validated; retry on stragglers ----
    if (haveA || haveB) {
      for (;;) {
        if (haveA && haveB) gload4i_x(fa[0], pA + f0);
        if (haveA) {
#pragma unroll
          for (int kt = 1; kt < 8; ++kt)
            gload4i_x(fa[kt], pA + (((size_t)((kt * 4 + kq) * 64 + arow)) << 3));
        }
        if (haveB) {
#pragma unroll
          for (int kt = 1; kt < 8; ++kt)
            gload4i_x(fb[kt], pB + (((size_t)((kt * 4 + kq) * 64 + arow)) << 3));
        }
        wait_vm0();
        int ok = 1;
        if (haveA && haveB) ok &= vld4(fa[0]);
        if (haveA) {
#pragma unroll
          for (int kt = 1; kt < 8; ++kt) ok &= vld4(fa[kt]);
        }
        if (haveB) {
#pragma unroll
          for (int kt = 1; kt < 8; ++kt) ok &= vld4(fb[kt]);
        }
        if (__all(ok)) break;
        __builtin_amdgcn_s_sleep(1);
      }
    }

    // ---- MFMA ----
    floatx4 acc0 = {0.f, 0.f, 0.f, 0.f};
    floatx4 acc1 = {0.f, 0.f, 0.f, 0.f};
    if (haveA) {
#pragma unroll
      for (int kt = 0; kt < 8; ++kt) {
        int kc = kt * 4 + kq;
        half8 w0 = *(const half8*)(wlds + ((kc * 32 + n0) << 3));
        half8 w1 = *(const half8*)(wlds + ((kc * 32 + n1) << 3));
        acc0 = __builtin_amdgcn_mfma_f32_16x16x32_f16(as_h8(fa[kt]), w0, acc0, 0, 0, 0);
        acc1 = __builtin_amdgcn_mfma_f32_16x16x32_f16(as_h8(fa[kt]), w1, acc1, 0, 0, 0);
      }
    }
    if (haveB) {
#pragma unroll
      for (int kt = 0; kt < 8; ++kt) {
        int kc = kt * 4 + kq;
        half8 w0 = *(const half8*)(wlds + (((32 + kc) * 32 + n0) << 3));
        half8 w1 = *(const half8*)(wlds + (((32 + kc) * 32 + n1) << 3));
        acc0 = __builtin_amdgcn_mfma_f32_16x16x32_f16(as_h8(fb[kt]), w0, acc0, 0, 0, 0);
        acc1 = __builtin_amdgcn_mfma_f32_16x16x32_f16(as_h8(fb[kt]), w1, acc1, 0, 0, 0);
      }
    }

    // ---- gates to LDS (C layout: col=lane&15, row=quad*4+reg) ----
    {
      int rbase = p * 16 + kq * 4;
#pragma unroll
      for (int r = 0; r < 4; ++r) {
        glds[(rbase + r) * 33 + n0]      = acc0[r];
        glds[(rbase + r) * 33 + 16 + n0] = acc1[r];
      }
    }
    __syncthreads();   // barrier B

    // ---- cell update: thread handles (bb, 2p) and (bb, 2p+1) ----
    {
      int xv = 0;
      if (l == 0) xv = x[bb * TT + t];
      float h0, h1;
#pragma unroll
      for (int q = 0; q < 2; ++q) {
        int j = 2 * p + q;
        float gi = glds[bb * 33 + j]      + blds[j];
        float gf = glds[bb * 33 + 8 + j]  + blds[8 + j];
        float gg = glds[bb * 33 + 16 + j] + blds[16 + j];
        float go = glds[bb * 33 + 24 + j] + blds[24 + j];
        if (l == 0) {
          const float* tb = tlds + xv * NR;
          gi += tb[j]; gf += tb[8 + j]; gg += tb[16 + j]; go += tb[24 + j];
        }
        float iv = sigm(gi), fv = sigm(gf), gv = tanh_f(gg), ov = sigm(go);
        float cv = (q == 0) ? c0 : c1;
        cv = fv * cv + iv * gv;
        float hv = ov * tanh_f(cv);
        if (q == 0) { c0 = cv; h0 = hv; } else { c1 = cv; h1 = hv; }
      }
      hl[t & 1][bb * 8 + 2 * p]     = (_Float16)h0;
      hl[t & 1][bb * 8 + 2 * p + 1] = (_Float16)h1;
    }
    __syncthreads();   // barrier C: hl[t&1] complete

    // ---- publish: ONE fire-and-forget instruction (64 lanes x 16B), sentinel-
    //      nudged. No ack, no flag -- release cost leaves the critical chain.
    //      (wave0's outstanding store drains inside its next spin wait.) ----
    if (tid < 64) {
      intx4 hv = *(const intx4*)(hl[t & 1] + tid * 8);
#pragma unroll
      for (int j = 0; j < 4; ++j)
        if (hv[j] == POISON) hv[j] ^= 1;   // 1-ulp nudge keeps sentinel unambiguous
      gstore4i_x(hrec + (size_t)t * TSTRIDE + ((size_t)w * 64 + tid) * 8, hv);
    }
  }
}

// ---------------------------------------------------------------------------
// Final projection, batch-split 4-way: grid (TT, 4).
// out[b][t][v] = h7[b][t][:] . fc_w[v][:] + fc_b[v]
__global__ __launch_bounds__(256) void fc_kernel(
    const _Float16* __restrict__ hseq7,  // [T][32][64][8] fp16
    const float* __restrict__ fcw,       // [23][256]
    const float* __restrict__ fcb,       // [23]
    float* __restrict__ out)             // [64][512][23]
{
  const int t   = blockIdx.x;
  const int bq  = blockIdx.y;            // batch quarter (16 rows)
  const int tid = threadIdx.x;
  __shared__ __align__(16) _Float16 hbuf[32 * 16 * 8];  // [kc][r][8], 8 KB
  __shared__ float wbuf[23 * 256];
  __shared__ float bbuf[24];

  const _Float16* src = hseq7 + (size_t)t * TSTRIDE;
  for (int i = tid; i < 32 * 16; i += 256)
    ((half8*)hbuf)[i] = *(const half8*)(src + ((size_t)((i >> 4) * 64 + bq * 16 + (i & 15)) << 3));
  for (int i = tid; i < 23 * 256; i += 256) wbuf[i] = fcw[i];
  if (tid < 23) bbuf[tid] = fcb[tid];
  __syncthreads();

  for (int o = tid; o < 16 * 23; o += 256) {
    int r = o / 23, v = o - r * 23;
    float acc = bbuf[v];
#pragma unroll 4
    for (int kc = 0; kc < 32; ++kc) {
      half8 hv = *(const half8*)(hbuf + ((kc * 16 + r) << 3));
      const float* wr = wbuf + v * 256 + kc * 8;
#pragma unroll
      for (int j = 0; j < 8; ++j) acc += (float)hv[j] * wr[j];
    }
    out[((size_t)(bq * 16 + r) * TT + t) * 23 + v] = acc;
  }
}

// ---------------------------------------------------------------------------
extern "C" void kernel_launch(void* const* d_in, const int* in_sizes, int n_in,
                              void* d_out, int out_size, void* d_ws, size_t ws_size,
                              hipStream_t stream) {
  const int*   x        = (const int*)d_in[0];
  const float* emb      = (const float*)d_in[1];
  const float* Wih0     = (const float*)d_in[2];
  const float* Wih_rest = (const float*)d_in[3];
  const float* Whh      = (const float*)d_in[4];
  const float* bihp     = (const float*)d_in[5];
  const float* bhhp     = (const float*)d_in[6];
  const float* fcw      = (const float*)d_in[7];
  const float* fcb      = (const float*)d_in[8];
  float* out = (float*)d_out;

  char* ws = (char*)d_ws;
  // ws layout (proven footprint): table @16384 | hseq @131072 (128MB)
  float*    table = (float*)(ws + 16384);              // 23*1024*4 = 94208 B
  _Float16* hseq  = (_Float16*)(ws + 131072);          // 8 * 16 MB

  // Pre-poison hseq (~20us): the sentinel protocol's only precondition,
  // independent of harness poisoning semantics. (R8-proven, incl. graph replay.)
  hipMemsetAsync(hseq, 0xAA, NL * LSTRIDE * sizeof(_Float16), stream);
  build_xg0<<<(23 * G4 + 255) / 256, 256, 0, stream>>>(emb, Wih0, table);
  lstm_pipeline<<<NL * NW, 256, 0, stream>>>(x, Wih_rest, Whh, bihp, bhhp, table, hseq);
  fc_kernel<<<dim3(TT, 4), 256, 0, stream>>>(hseq + (size_t)7 * LSTRIDE, fcw, fcb, out);
}